// Round 6
// baseline (4071.732 us; speedup 1.0000x reference)
//
#include <hip/hip_runtime.h>
#include <hip/hip_bf16.h>

using bf16 = __hip_bfloat16;
typedef __attribute__((ext_vector_type(8))) short short8;  // 8 bf16 (4 VGPRs)
typedef __attribute__((ext_vector_type(4))) float f32x4;   // MFMA C/D

static constexpr int NN = 100000;   // nodes
static constexpr int NE = 1600000;  // message edges
static constexpr int NS = 500000;   // scored edges
static constexpr int HH = 64;       // hidden
static constexpr int SCAN_B = 1024;
static constexpr int SCAN_G = (NN + SCAN_B - 1) / SCAN_B;   // 98
static constexpr int DPW = 8;       // dsts per wave (mfma aggregate)

__device__ __forceinline__ float b2f(bf16 v) { return __bfloat162float(v); }
__device__ __forceinline__ bf16  f2b(float v) { return __float2bfloat16(v); }
__device__ __forceinline__ ushort f2bu(float v) { return __bfloat16_as_ushort(__float2bfloat16(v)); }
__device__ __forceinline__ float bcast(float v, int k) {
    return __uint_as_float(__builtin_amdgcn_readlane(__float_as_uint(v), k));
}

// ---------------- encode + weight prep ----------------

__global__ void encode_nodes_k(const float* __restrict__ x, const float* __restrict__ Wn,
                               const float* __restrict__ bn, float* __restrict__ h) {
    int tid = blockIdx.x * blockDim.x + threadIdx.x;
    if (tid >= NN * HH) return;
    int r = tid >> 6, j = tid & 63;
    h[tid] = fmaf(x[2 * r], Wn[j], fmaf(x[2 * r + 1], Wn[HH + j], bn[j]));
}

// Fold edge encoder into layer-0 C: We0 = We@C0 (2x64), bb0 = be@C0 + cb0
__global__ void prep_k(const float* __restrict__ We, const float* __restrict__ be,
                       const float* __restrict__ C0, const float* __restrict__ cb0,
                       float* __restrict__ We0, float* __restrict__ bb0) {
    int j = threadIdx.x;
    if (j >= HH) return;
    float s0 = 0.f, s1 = 0.f, sb = 0.f;
    for (int k = 0; k < HH; ++k) {
        float c = C0[k * HH + j];
        s0 = fmaf(We[k], c, s0);
        s1 = fmaf(We[HH + k], c, s1);
        sb = fmaf(be[k], c, sb);
    }
    We0[j] = s0; We0[HH + j] = s1; bb0[j] = sb + cb0[j];
}

// ---------------- CSR build (counting sort by dst) ----------------

__global__ void zero_int_k(int* __restrict__ p, int n) {
    int i = blockIdx.x * blockDim.x + threadIdx.x;
    if (i < n) p[i] = 0;
}

__global__ void hist_k(const int* __restrict__ dst, int* __restrict__ cnt) {
    int i = blockIdx.x * blockDim.x + threadIdx.x;
    if (i < NE) atomicAdd(&cnt[dst[i]], 1);
}

__global__ void scan1_k(const int* __restrict__ cnt, int* __restrict__ rowptr,
                        int* __restrict__ bsum) {
    __shared__ int sm[SCAN_B];
    int t = threadIdx.x, idx = blockIdx.x * SCAN_B + t;
    int v = (idx < NN) ? cnt[idx] : 0;
    sm[t] = v;
    __syncthreads();
    for (int off = 1; off < SCAN_B; off <<= 1) {
        int add = (t >= off) ? sm[t - off] : 0;
        __syncthreads();
        sm[t] += add;
        __syncthreads();
    }
    if (idx < NN) rowptr[idx] = sm[t] - v;
    if (t == SCAN_B - 1) bsum[blockIdx.x] = sm[t];
}

__global__ void scan2_k(const int* __restrict__ bsum, int* __restrict__ bofs) {
    if (threadIdx.x == 0) {
        int acc = 0;
        for (int b = 0; b < SCAN_G; ++b) { bofs[b] = acc; acc += bsum[b]; }
    }
}

__global__ void scan3_k(int* __restrict__ rowptr, int* __restrict__ cursor,
                        const int* __restrict__ bofs) {
    int idx = blockIdx.x * SCAN_B + threadIdx.x;
    if (idx < NN) {
        int r = rowptr[idx] + bofs[blockIdx.x];
        rowptr[idx] = r;
        cursor[idx] = r;
    }
    if (idx == 0) rowptr[NN] = NE;
}

__global__ void scatter_k(const int* __restrict__ dst, int* __restrict__ cursor,
                          int* __restrict__ perm) {
    int i = blockIdx.x * blockDim.x + threadIdx.x;
    if (i < NE) {
        int p = atomicAdd(&cursor[dst[i]], 1);
        perm[p] = i;
    }
}

// ---------------- per-layer node transforms ----------------
__global__ __launch_bounds__(256, 2)
void node_transform_k(const float* __restrict__ h, const float* __restrict__ A,
                      const float* __restrict__ B, const float* __restrict__ V,
                      bf16* __restrict__ oA, bf16* __restrict__ oB, bf16* __restrict__ oV) {
    int lane = threadIdx.x & 63;
    const float* W; bf16* out;
    if (blockIdx.y == 0)      { W = A; out = oA; }
    else if (blockIdx.y == 1) { W = B; out = oB; }
    else                      { W = V; out = oV; }
    float col[HH];
#pragma unroll
    for (int k = 0; k < HH; ++k) col[k] = W[k * HH + lane];
    int wave = blockIdx.x * (blockDim.x >> 6) + (threadIdx.x >> 6);
    int nw = gridDim.x * (blockDim.x >> 6);
    for (int r = wave; r < NN; r += nw) {
        const float* hr = h + (size_t)r * HH;
        float acc = 0.f;
#pragma unroll
        for (int k = 0; k < HH; ++k) acc = fmaf(hr[k], col[k], acc);
        out[(size_t)r * HH + lane] = f2b(acc);
    }
}

// ---------------- layer-0 aggregate (scalar; no chain matvec needed) ----------------
__global__ __launch_bounds__(256, 2)
void aggregate0_k(float* __restrict__ h, const bf16* __restrict__ tabs,
                  const bf16* __restrict__ hV,
                  const float* __restrict__ We0, const float* __restrict__ bb0,
                  const float* __restrict__ Ul,
                  const int* __restrict__ rowptr, const int* __restrict__ perm,
                  const int* __restrict__ src, const float2* __restrict__ e0) {
    int lane = threadIdx.x & 63;
    float w0 = We0[lane], w1 = We0[HH + lane], b0 = bb0[lane];
    const size_t nb = (size_t)NN * HH;

    int d = blockIdx.x * 4 + (threadIdx.x >> 6);
    if (d >= NN) return;
    d = __builtin_amdgcn_readfirstlane(d);
    int beg = rowptr[d], end = rowptr[d + 1];
    size_t drow = (size_t)d * HH + lane;
    float bB0 = b2f(tabs[nb + drow]);

    float num = 0.f, den = 0.f;
    for (int i = beg; i < end; ++i) {
        int e = __builtin_amdgcn_readfirstlane(perm[i]);
        int s = __builtin_amdgcn_readfirstlane(src[e]);
        size_t srow = (size_t)s * HH + lane;
        float2 ev = e0[e];
        float z = fmaf(ev.x, w0, fmaf(ev.y, w1, b0)) + b2f(tabs[srow]) + bB0;
        float sig = 1.f / (1.f + __expf(-z));
        num = fmaf(sig, b2f(hV[srow]), num);
        den += sig;
    }
    float hd = h[drow];
    float hu = 0.f;
#pragma unroll
    for (int k = 0; k < HH; ++k) hu = fmaf(bcast(hd, k), Ul[k * HH + lane], hu);
    h[drow] = fmaxf(hu + num / (den + 1e-6f), 0.f);
}

// ---------------- layers 1/2 aggregate: MFMA edge-batch chain ----------------
// Per wave: DPW dsts; per dst, edges in batches of 16.
// A-frag (16x32 bf16): lane holds row=l&15, k=(l>>4)*8+j (j=0..7)
// B-frag (32x16 bf16): lane holds col=l&15, k=(l>>4)*8+j
// C/D: col=lane&15, row=(lane>>4)*4+reg  [m89-verified]
template <int LAYER>
__global__ __launch_bounds__(256, 2)
void aggregate_mfma_k(float* __restrict__ h, const bf16* __restrict__ tabs,
                      const bf16* __restrict__ hV,
                      const float* __restrict__ We0, const float* __restrict__ bb0,
                      const float* __restrict__ cb, const float* __restrict__ C,
                      const float* __restrict__ Ul,
                      const int* __restrict__ rowptr, const int* __restrict__ perm,
                      const int* __restrict__ src, const float2* __restrict__ e0) {
    __shared__ __align__(16) char lds_all[4 * 4096];
    char* lds = lds_all + (threadIdx.x >> 6) * 4096;
    const int lane = threadIdx.x & 63;
    const int l15 = lane & 15, lg = lane >> 4;
    const size_t nb = (size_t)NN * HH;

    // B-fragments of C1 (and C2) resident in VGPRs (32 regs per matrix)
    short8 bf1[4][2], bf2[4][2];
    {
        const float* C1 = C + 1 * HH * HH;
        const float* C2 = C + 2 * HH * HH;
#pragma unroll
        for (int t = 0; t < 4; ++t)
#pragma unroll
            for (int f = 0; f < 2; ++f) {
                short8 v1, v2;
#pragma unroll
                for (int j = 0; j < 8; ++j) {
                    int k = f * 32 + lg * 8 + j;
                    v1[j] = (short)f2bu(C1[k * HH + t * 16 + l15]);
                    if constexpr (LAYER >= 2) v2[j] = (short)f2bu(C2[k * HH + t * 16 + l15]);
                }
                bf1[t][f] = v1;
                if constexpr (LAYER >= 2) bf2[t][f] = v2;
            }
    }
    float w0 = We0[lane], w1 = We0[HH + lane], b0 = bb0[lane];
    float cb1t[4], cb2t[4];
#pragma unroll
    for (int t = 0; t < 4; ++t) {
        cb1t[t] = cb[HH + t * 16 + l15];
        if constexpr (LAYER >= 2) cb2t[t] = cb[2 * HH + t * 16 + l15];
    }

    int w = blockIdx.x * 4 + (threadIdx.x >> 6);
    int dA = w * DPW, dZ = min(dA + DPW, NN);
    for (int d = dA; d < dZ; ++d) {
        int beg = rowptr[d], end = rowptr[d + 1];
        size_t drow = (size_t)d * HH;
        float zc0 = b0 + b2f(tabs[nb + drow + lane]);        // bb0 + B0[d]
        float c1d[4], c2d[4];
#pragma unroll
        for (int t = 0; t < 4; ++t) {
            c1d[t] = cb1t[t] + b2f(tabs[3 * nb + drow + t * 16 + l15]);
            if constexpr (LAYER >= 2)
                c2d[t] = cb2t[t] + b2f(tabs[5 * nb + drow + t * 16 + l15]);
        }
        float nm = 0.f, dn = 0.f;

        for (int b = beg; b < end; b += 16) {
            // phase 1: z0 per edge (lane = feature), relu -> bf16 LDS (swizzled)
#pragma unroll
            for (int sl = 0; sl < 16; ++sl) {
                int eid = perm[min(b + sl, end - 1)];
                int s = src[eid];
                float2 ev = e0[eid];
                float z = fmaf(ev.x, w0, fmaf(ev.y, w1, zc0)) +
                          b2f(tabs[(size_t)s * HH + lane]);
                *(ushort*)(lds + ((sl * 128 + lane * 2) ^ ((sl & 7) << 4))) =
                    f2bu(fmaxf(z, 0.f));
            }
            // src ids for this wave-lane's D rows (row = lg*4 + r)
            int sA[4];
#pragma unroll
            for (int r = 0; r < 4; ++r)
                sA[r] = src[perm[min(b + lg * 4 + r, end - 1)]];

            // A-frags from LDS
            short8 af0, af1;
            __builtin_memcpy(&af0, lds + ((l15 * 128 + lg * 16) ^ ((l15 & 7) << 4)), 16);
            __builtin_memcpy(&af1, lds + ((l15 * 128 + 64 + lg * 16) ^ ((l15 & 7) << 4)), 16);

            // chain1: acc = bias1 (D layout) + e1 @ C1
            f32x4 acc[4];
#pragma unroll
            for (int t = 0; t < 4; ++t) {
                f32x4 a;
#pragma unroll
                for (int r = 0; r < 4; ++r)
                    a[r] = c1d[t] + b2f(tabs[2 * nb + (size_t)sA[r] * HH + t * 16 + l15]);
                acc[t] = a;
            }
#pragma unroll
            for (int t = 0; t < 4; ++t) {
                acc[t] = __builtin_amdgcn_mfma_f32_16x16x32_bf16(af0, bf1[t][0], acc[t], 0, 0, 0);
                acc[t] = __builtin_amdgcn_mfma_f32_16x16x32_bf16(af1, bf1[t][1], acc[t], 0, 0, 0);
            }

            if constexpr (LAYER >= 2) {
                // relu -> bf16 LDS (D-layout positions), re-read A-frags
#pragma unroll
                for (int t = 0; t < 4; ++t)
#pragma unroll
                    for (int r = 0; r < 4; ++r) {
                        int row = lg * 4 + r;
                        *(ushort*)(lds + ((row * 128 + (t * 16 + l15) * 2) ^ ((row & 7) << 4))) =
                            f2bu(fmaxf(acc[t][r], 0.f));
                    }
                __builtin_memcpy(&af0, lds + ((l15 * 128 + lg * 16) ^ ((l15 & 7) << 4)), 16);
                __builtin_memcpy(&af1, lds + ((l15 * 128 + 64 + lg * 16) ^ ((l15 & 7) << 4)), 16);
#pragma unroll
                for (int t = 0; t < 4; ++t) {
                    f32x4 a;
#pragma unroll
                    for (int r = 0; r < 4; ++r)
                        a[r] = c2d[t] + b2f(tabs[4 * nb + (size_t)sA[r] * HH + t * 16 + l15]);
                    acc[t] = a;
                }
#pragma unroll
                for (int t = 0; t < 4; ++t) {
                    acc[t] = __builtin_amdgcn_mfma_f32_16x16x32_bf16(af0, bf2[t][0], acc[t], 0, 0, 0);
                    acc[t] = __builtin_amdgcn_mfma_f32_16x16x32_bf16(af1, bf2[t][1], acc[t], 0, 0, 0);
                }
            }

            // sigmoid -> f32 LDS [row*256 + feat*4]
#pragma unroll
            for (int t = 0; t < 4; ++t)
#pragma unroll
                for (int r = 0; r < 4; ++r) {
                    int row = lg * 4 + r;
                    float sg = 1.f / (1.f + __expf(-acc[t][r]));
                    *(float*)(lds + row * 256 + (t * 16 + l15) * 4) = sg;
                }

            // aggregation over the real edges of this batch (lane = feature)
            int cnt = min(end - b, 16);
            for (int sl = 0; sl < cnt; ++sl) {
                int eid = perm[b + sl];
                int s = src[eid];
                float sg = *(const float*)(lds + sl * 256 + lane * 4);
                nm = fmaf(sg, b2f(hV[(size_t)s * HH + lane]), nm);
                dn += sg;
            }
        }

        // fused: h[d] = relu(h[d]@U_l + num/(den+1e-6))
        float hd = h[drow + lane];
        float hu = 0.f;
#pragma unroll
        for (int k = 0; k < HH; ++k)
            hu = fmaf(bcast(hd, k), Ul[k * HH + lane], hu);
        h[drow + lane] = fmaxf(hu + nm / (dn + 1e-6f), 0.f);
    }
}

// ---------------- scoring ----------------
__global__ void score_k(const float* __restrict__ h, const float* __restrict__ Wp,
                        const float* __restrict__ bp, const int* __restrict__ ss,
                        const int* __restrict__ ds, float* __restrict__ out) {
    int lane = threadIdx.x & 63;
    int wave = (blockIdx.x * blockDim.x + threadIdx.x) >> 6;
    if (wave >= NS) return;
    int s = ss[wave], d = ds[wave];
    float v = fmaf(h[(size_t)s * HH + lane], Wp[lane],
                   h[(size_t)d * HH + lane] * Wp[HH + lane]);
#pragma unroll
    for (int off = 32; off; off >>= 1) v += __shfl_xor(v, off);
    if (lane == 0) out[wave] = v + bp[0];
}

extern "C" void kernel_launch(void* const* d_in, const int* in_sizes, int n_in,
                              void* d_out, int out_size, void* d_ws, size_t ws_size,
                              hipStream_t stream) {
    const float* x  = (const float*)d_in[0];
    const float* e0 = (const float*)d_in[1];
    const float* Wn = (const float*)d_in[2];
    const float* bn = (const float*)d_in[3];
    const float* We = (const float*)d_in[4];
    const float* be = (const float*)d_in[5];
    const float* A  = (const float*)d_in[6];
    const float* B  = (const float*)d_in[7];
    const float* C  = (const float*)d_in[8];
    const float* cb = (const float*)d_in[9];
    const float* U  = (const float*)d_in[10];
    const float* V  = (const float*)d_in[11];
    const float* Wp = (const float*)d_in[12];
    const float* bp = (const float*)d_in[13];
    const int* src  = (const int*)d_in[14];
    const int* dst  = (const int*)d_in[15];
    const int* ss   = (const int*)d_in[16];
    const int* ds   = (const int*)d_in[17];

    char* ws = (char*)d_ws;
    size_t nb = (size_t)NN * HH;
    float* h      = (float*)ws;                    // 25.6 MB
    bf16*  tabs   = (bf16*)(ws + nb * 4);          // 6 x 12.8 MB
    bf16*  hV     = tabs + 6 * nb;                 // 12.8 MB
    int*   perm   = (int*)(hV + nb);               // 6.4 MB
    int*   cnt    = perm + NE;
    int*   rowptr = cnt + NN;
    int*   cursor = rowptr + (NN + 1);
    int*   bsum   = cursor + NN;
    int*   bofs   = bsum + SCAN_G;
    float* We0    = (float*)(bofs + SCAN_G);
    float* bb0    = We0 + 2 * HH;

    encode_nodes_k<<<(NN * HH + 255) / 256, 256, 0, stream>>>(x, Wn, bn, h);
    prep_k<<<1, 64, 0, stream>>>(We, be, C, cb, We0, bb0);

    zero_int_k<<<(NN + 255) / 256, 256, 0, stream>>>(cnt, NN);
    hist_k<<<(NE + 255) / 256, 256, 0, stream>>>(dst, cnt);
    scan1_k<<<SCAN_G, SCAN_B, 0, stream>>>(cnt, rowptr, bsum);
    scan2_k<<<1, 64, 0, stream>>>(bsum, bofs);
    scan3_k<<<SCAN_G, SCAN_B, 0, stream>>>(rowptr, cursor, bofs);
    scatter_k<<<(NE + 255) / 256, 256, 0, stream>>>(dst, cursor, perm);

    int mgrid = (NN + 4 * DPW - 1) / (4 * DPW);   // 3125
    for (int l = 0; l < 3; ++l) {
        node_transform_k<<<dim3(512, 3), 256, 0, stream>>>(
            h, A + (size_t)l * HH * HH, B + (size_t)l * HH * HH, V + (size_t)l * HH * HH,
            tabs + 2 * (size_t)l * nb, tabs + (2 * (size_t)l + 1) * nb, hV);
        const float* Ul = U + (size_t)l * HH * HH;
        if (l == 0)
            aggregate0_k<<<(NN + 3) / 4, 256, 0, stream>>>(
                h, tabs, hV, We0, bb0, Ul, rowptr, perm, src, (const float2*)e0);
        else if (l == 1)
            aggregate_mfma_k<1><<<mgrid, 256, 0, stream>>>(
                h, tabs, hV, We0, bb0, cb, C, Ul, rowptr, perm, src, (const float2*)e0);
        else
            aggregate_mfma_k<2><<<mgrid, 256, 0, stream>>>(
                h, tabs, hV, We0, bb0, cb, C, Ul, rowptr, perm, src, (const float2*)e0);
    }

    score_k<<<(int)(((size_t)NS * HH + 255) / 256), 256, 0, stream>>>(
        h, Wp, bp, ss, ds, (float*)d_out);
}

// Round 7
// 2640.749 us; speedup vs baseline: 1.5419x; 1.5419x over previous
//
#include <hip/hip_runtime.h>
#include <hip/hip_bf16.h>

using bf16 = __hip_bfloat16;
typedef __attribute__((ext_vector_type(8))) short short8;  // 8 bf16 (4 VGPRs)
typedef __attribute__((ext_vector_type(4))) float f32x4;   // MFMA C/D
typedef __attribute__((ext_vector_type(4))) int   iv4;     // 16B of packed bf16

static constexpr int NN = 100000;   // nodes
static constexpr int NE = 1600000;  // message edges
static constexpr int NS = 500000;   // scored edges
static constexpr int HH = 64;       // hidden
static constexpr int SCAN_B = 1024;
static constexpr int SCAN_G = (NN + SCAN_B - 1) / SCAN_B;   // 98
static constexpr int DPW = 4;       // dsts per wave (aggregate)

__device__ __forceinline__ float b2f(bf16 v) { return __bfloat162float(v); }
__device__ __forceinline__ bf16  f2b(float v) { return __float2bfloat16(v); }
__device__ __forceinline__ float bflo(int u)  { return __uint_as_float(((unsigned)u) << 16); }
__device__ __forceinline__ float bfhi(int u)  { return __uint_as_float(((unsigned)u) & 0xffff0000u); }
__device__ __forceinline__ int pk2(float a, float b) {
    unsigned lo = __bfloat16_as_ushort(__float2bfloat16(a));
    unsigned hi = __bfloat16_as_ushort(__float2bfloat16(b));
    return (int)(lo | (hi << 16));
}
__device__ __forceinline__ float bcast(float v, int k) {
    return __uint_as_float(__builtin_amdgcn_readlane(__float_as_uint(v), k));
}

// ---------------- encode + weight prep ----------------

__global__ void encode_nodes_k(const float* __restrict__ x, const float* __restrict__ Wn,
                               const float* __restrict__ bn, float* __restrict__ h) {
    int tid = blockIdx.x * blockDim.x + threadIdx.x;
    if (tid >= NN * HH) return;
    int r = tid >> 6, j = tid & 63;
    h[tid] = fmaf(x[2 * r], Wn[j], fmaf(x[2 * r + 1], Wn[HH + j], bn[j]));
}

// Fold edge encoder into layer-0 C: We0 = We@C0 (2x64), bb0 = be@C0 + cb0
__global__ void prep_k(const float* __restrict__ We, const float* __restrict__ be,
                       const float* __restrict__ C0, const float* __restrict__ cb0,
                       float* __restrict__ We0, float* __restrict__ bb0) {
    int j = threadIdx.x;
    if (j >= HH) return;
    float s0 = 0.f, s1 = 0.f, sb = 0.f;
    for (int k = 0; k < HH; ++k) {
        float c = C0[k * HH + j];
        s0 = fmaf(We[k], c, s0);
        s1 = fmaf(We[HH + k], c, s1);
        sb = fmaf(be[k], c, sb);
    }
    We0[j] = s0; We0[HH + j] = s1; bb0[j] = sb + cb0[j];
}

// ---------------- CSR build (counting sort by dst) ----------------

__global__ void zero_int_k(int* __restrict__ p, int n) {
    int i = blockIdx.x * blockDim.x + threadIdx.x;
    if (i < n) p[i] = 0;
}

__global__ void hist_k(const int* __restrict__ dst, int* __restrict__ cnt) {
    int i = blockIdx.x * blockDim.x + threadIdx.x;
    if (i < NE) atomicAdd(&cnt[dst[i]], 1);
}

__global__ void scan1_k(const int* __restrict__ cnt, int* __restrict__ rowptr,
                        int* __restrict__ bsum) {
    __shared__ int sm[SCAN_B];
    int t = threadIdx.x, idx = blockIdx.x * SCAN_B + t;
    int v = (idx < NN) ? cnt[idx] : 0;
    sm[t] = v;
    __syncthreads();
    for (int off = 1; off < SCAN_B; off <<= 1) {
        int add = (t >= off) ? sm[t - off] : 0;
        __syncthreads();
        sm[t] += add;
        __syncthreads();
    }
    if (idx < NN) rowptr[idx] = sm[t] - v;
    if (t == SCAN_B - 1) bsum[blockIdx.x] = sm[t];
}

__global__ void scan2_k(const int* __restrict__ bsum, int* __restrict__ bofs) {
    if (threadIdx.x == 0) {
        int acc = 0;
        for (int b = 0; b < SCAN_G; ++b) { bofs[b] = acc; acc += bsum[b]; }
    }
}

__global__ void scan3_k(int* __restrict__ rowptr, int* __restrict__ cursor,
                        const int* __restrict__ bofs) {
    int idx = blockIdx.x * SCAN_B + threadIdx.x;
    if (idx < NN) {
        int r = rowptr[idx] + bofs[blockIdx.x];
        rowptr[idx] = r;
        cursor[idx] = r;
    }
    if (idx == 0) rowptr[NN] = NE;
}

__global__ void scatter_k(const int* __restrict__ dst, int* __restrict__ cursor,
                          int* __restrict__ perm) {
    int i = blockIdx.x * blockDim.x + threadIdx.x;
    if (i < NE) {
        int p = atomicAdd(&cursor[dst[i]], 1);
        perm[p] = i;
    }
}

// ---------------- per-layer node transforms (wave per row, 4-way ILP) ----------------
__global__ __launch_bounds__(256, 2)
void node_transform_k(const float* __restrict__ h, const float* __restrict__ A,
                      const float* __restrict__ B, const float* __restrict__ V,
                      bf16* __restrict__ oA, bf16* __restrict__ oB, bf16* __restrict__ oV) {
    int lane = threadIdx.x & 63;
    const float* W; bf16* out;
    if (blockIdx.y == 0)      { W = A; out = oA; }
    else if (blockIdx.y == 1) { W = B; out = oB; }
    else                      { W = V; out = oV; }
    float col[HH];
#pragma unroll
    for (int k = 0; k < HH; ++k) col[k] = W[k * HH + lane];
    int wave = blockIdx.x * (blockDim.x >> 6) + (threadIdx.x >> 6);
    int nw = gridDim.x * (blockDim.x >> 6);
    for (int r = wave; r < NN; r += nw) {
        const float* hr = h + (size_t)r * HH;
        float a0 = 0.f, a1 = 0.f, a2 = 0.f, a3 = 0.f;
#pragma unroll
        for (int k = 0; k < HH; k += 4) {
            a0 = fmaf(hr[k],     col[k],     a0);
            a1 = fmaf(hr[k + 1], col[k + 1], a1);
            a2 = fmaf(hr[k + 2], col[k + 2], a2);
            a3 = fmaf(hr[k + 3], col[k + 3], a3);
        }
        out[(size_t)r * HH + lane] = f2b((a0 + a1) + (a2 + a3));
    }
}

// ---------------- fused aggregate + node update (lane-parallel, MFMA chains) ------
// tabs layout: [A0,B0,A1,B1,A2,B2] each [NN*64] bf16.
// A-frag: lane l -> edge=l&15, k=(l>>4)*8+j (af0), +32 (af1)   [verified r6]
// B-frag: lane l -> col=t*16+(l&15), k=(l>>4)*8+j (+32)        [verified r6]
// D:      lane l -> col=t*16+(l&15), row(edge)=(l>>4)*4+r      [verified r6/m89]
template <int LAYER>
__global__ __launch_bounds__(256, 2)
void agg_k(float* __restrict__ h, const bf16* __restrict__ tabs,
           const bf16* __restrict__ hV,
           const float* __restrict__ We0, const float* __restrict__ bb0,
           const float* __restrict__ cb, const float* __restrict__ C,
           const float* __restrict__ Ul,
           const int* __restrict__ rowptr, const int* __restrict__ perm,
           const int* __restrict__ src, const float2* __restrict__ e0) {
    __shared__ __align__(16) char lds_all[4 * 2048];
    char* lds = lds_all + (threadIdx.x >> 6) * 2048;
    const int lane = threadIdx.x & 63;
    const int l15 = lane & 15, lg = lane >> 4, kb = lg * 8;
    const size_t nb = (size_t)NN * HH;

    // persistent per-lane constants (feature-indexed by this lane's A-frag k's)
    float w0a[8], w0b[8], w1a[8], w1b[8], bba[8], bbb[8];
#pragma unroll
    for (int j = 0; j < 8; ++j) {
        w0a[j] = We0[kb + j];        w0b[j] = We0[32 + kb + j];
        w1a[j] = We0[HH + kb + j];   w1b[j] = We0[HH + 32 + kb + j];
        bba[j] = bb0[kb + j];        bbb[j] = bb0[32 + kb + j];
    }
    short8 bf1[4][2], bf2[4][2];
    float cb1t[4], cb2t[4];
    if constexpr (LAYER >= 1) {
        const float* C1 = C + 1 * HH * HH;
#pragma unroll
        for (int t = 0; t < 4; ++t) {
            cb1t[t] = cb[HH + t * 16 + l15];
#pragma unroll
            for (int f = 0; f < 2; ++f) {
                iv4 q;
#pragma unroll
                for (int j = 0; j < 4; ++j)
                    q[j] = pk2(C1[(f * 32 + kb + 2 * j) * HH + t * 16 + l15],
                               C1[(f * 32 + kb + 2 * j + 1) * HH + t * 16 + l15]);
                __builtin_memcpy(&bf1[t][f], &q, 16);
            }
        }
    }
    if constexpr (LAYER >= 2) {
        const float* C2 = C + 2 * HH * HH;
#pragma unroll
        for (int t = 0; t < 4; ++t) {
            cb2t[t] = cb[2 * HH + t * 16 + l15];
#pragma unroll
            for (int f = 0; f < 2; ++f) {
                iv4 q;
#pragma unroll
                for (int j = 0; j < 4; ++j)
                    q[j] = pk2(C2[(f * 32 + kb + 2 * j) * HH + t * 16 + l15],
                               C2[(f * 32 + kb + 2 * j + 1) * HH + t * 16 + l15]);
                __builtin_memcpy(&bf2[t][f], &q, 16);
            }
        }
    }

    int w = blockIdx.x * 4 + (threadIdx.x >> 6);
    int dA = w * DPW, dZ = min(dA + DPW, NN);
    for (int d = dA; d < dZ; ++d) {
        int beg = rowptr[d], end = rowptr[d + 1];
        size_t drow = (size_t)d * HH;

        // per-dst biases
        float zba[8], zbb[8];
        {
            iv4 ra = *(const iv4*)(tabs + nb + drow + kb);        // B0[d] feats kb..kb+7
            iv4 rb = *(const iv4*)(tabs + nb + drow + 32 + kb);
#pragma unroll
            for (int q = 0; q < 4; ++q) {
                zba[2 * q]     = bba[2 * q]     + bflo(ra[q]);
                zba[2 * q + 1] = bba[2 * q + 1] + bfhi(ra[q]);
                zbb[2 * q]     = bbb[2 * q]     + bflo(rb[q]);
                zbb[2 * q + 1] = bbb[2 * q + 1] + bfhi(rb[q]);
            }
        }
        float c1d[4], c2d[4];
        if constexpr (LAYER >= 1) {
#pragma unroll
            for (int t = 0; t < 4; ++t)
                c1d[t] = cb1t[t] + b2f(tabs[3 * nb + drow + t * 16 + l15]);
        }
        if constexpr (LAYER >= 2) {
#pragma unroll
            for (int t = 0; t < 4; ++t)
                c2d[t] = cb2t[t] + b2f(tabs[5 * nb + drow + t * 16 + l15]);
        }

        float nmA[16], dnA[16], nmT[4], dnT[4];
        if constexpr (LAYER == 0) {
#pragma unroll
            for (int j = 0; j < 16; ++j) { nmA[j] = 0.f; dnA[j] = 0.f; }
        } else {
#pragma unroll
            for (int t = 0; t < 4; ++t) { nmT[t] = 0.f; dnT[t] = 0.f; }
        }

        for (int b = beg; b < end; b += 16) {
            int cnt = min(end - b, 16);
            int slot = (l15 < cnt) ? l15 : (cnt - 1);
            int ei = perm[b + slot];
            int s  = src[ei];
            float2 ev = e0[ei];
            // z0 (= e_hat0) in A-frag layout, fully lane-parallel
            float za[8], zc[8];
            {
                iv4 ra = *(const iv4*)(tabs + (size_t)s * HH + kb);
                iv4 rb = *(const iv4*)(tabs + (size_t)s * HH + 32 + kb);
#pragma unroll
                for (int q = 0; q < 4; ++q) {
                    za[2*q]   = fmaf(ev.x, w0a[2*q],   fmaf(ev.y, w1a[2*q],   zba[2*q]))   + bflo(ra[q]);
                    za[2*q+1] = fmaf(ev.x, w0a[2*q+1], fmaf(ev.y, w1a[2*q+1], zba[2*q+1])) + bfhi(ra[q]);
                    zc[2*q]   = fmaf(ev.x, w0b[2*q],   fmaf(ev.y, w1b[2*q],   zbb[2*q]))   + bflo(rb[q]);
                    zc[2*q+1] = fmaf(ev.x, w0b[2*q+1], fmaf(ev.y, w1b[2*q+1], zbb[2*q+1])) + bfhi(rb[q]);
                }
            }
            if constexpr (LAYER == 0) {
                bool valid = (l15 < cnt);
                iv4 ha = *(const iv4*)(hV + (size_t)s * HH + kb);
                iv4 hb = *(const iv4*)(hV + (size_t)s * HH + 32 + kb);
#pragma unroll
                for (int q = 0; q < 4; ++q) {
                    float s00 = valid ? 1.f / (1.f + __expf(-za[2*q]))   : 0.f;
                    float s01 = valid ? 1.f / (1.f + __expf(-za[2*q+1])) : 0.f;
                    float s10 = valid ? 1.f / (1.f + __expf(-zc[2*q]))   : 0.f;
                    float s11 = valid ? 1.f / (1.f + __expf(-zc[2*q+1])) : 0.f;
                    nmA[2*q]     = fmaf(s00, bflo(ha[q]), nmA[2*q]);     dnA[2*q]     += s00;
                    nmA[2*q+1]   = fmaf(s01, bfhi(ha[q]), nmA[2*q+1]);   dnA[2*q+1]   += s01;
                    nmA[8+2*q]   = fmaf(s10, bflo(hb[q]), nmA[8+2*q]);   dnA[8+2*q]   += s10;
                    nmA[8+2*q+1] = fmaf(s11, bfhi(hb[q]), nmA[8+2*q+1]); dnA[8+2*q+1] += s11;
                }
            } else {
                // relu -> bf16 A-frags directly (no LDS)
                iv4 pa, pb;
#pragma unroll
                for (int q = 0; q < 4; ++q) {
                    pa[q] = pk2(fmaxf(za[2*q], 0.f), fmaxf(za[2*q+1], 0.f));
                    pb[q] = pk2(fmaxf(zc[2*q], 0.f), fmaxf(zc[2*q+1], 0.f));
                }
                short8 af0, af1;
                __builtin_memcpy(&af0, &pa, 16);
                __builtin_memcpy(&af1, &pb, 16);
                int sA[4];
#pragma unroll
                for (int r = 0; r < 4; ++r) sA[r] = __shfl(s, lg * 4 + r);
                f32x4 acc[4];
#pragma unroll
                for (int t = 0; t < 4; ++t) {
                    f32x4 a;
#pragma unroll
                    for (int r = 0; r < 4; ++r)
                        a[r] = c1d[t] + b2f(tabs[2 * nb + (size_t)sA[r] * HH + t * 16 + l15]);
                    acc[t] = a;
                }
#pragma unroll
                for (int t = 0; t < 4; ++t) {
                    acc[t] = __builtin_amdgcn_mfma_f32_16x16x32_bf16(af0, bf1[t][0], acc[t], 0, 0, 0);
                    acc[t] = __builtin_amdgcn_mfma_f32_16x16x32_bf16(af1, bf1[t][1], acc[t], 0, 0, 0);
                }
                if constexpr (LAYER >= 2) {
                    // relu(e_hat1): D-layout -> swizzled LDS -> A-frags
#pragma unroll
                    for (int t = 0; t < 4; ++t)
#pragma unroll
                        for (int r = 0; r < 4; ++r) {
                            int row = lg * 4 + r;
                            int ad = (row * 128 + (t * 16 + l15) * 2) ^ ((row & 7) << 4);
                            *(unsigned short*)(lds + ad) =
                                __bfloat16_as_ushort(__float2bfloat16(fmaxf(acc[t][r], 0.f)));
                        }
                    asm volatile("s_waitcnt lgkmcnt(0)" ::: "memory");
                    short8 ag0, ag1;
                    {
                        int a0 = (l15 * 128 + kb * 2) ^ ((l15 & 7) << 4);
                        int a1 = (l15 * 128 + 64 + kb * 2) ^ ((l15 & 7) << 4);
                        __builtin_memcpy(&ag0, lds + a0, 16);
                        __builtin_memcpy(&ag1, lds + a1, 16);
                    }
#pragma unroll
                    for (int t = 0; t < 4; ++t) {
                        f32x4 a;
#pragma unroll
                        for (int r = 0; r < 4; ++r)
                            a[r] = c2d[t] + b2f(tabs[4 * nb + (size_t)sA[r] * HH + t * 16 + l15]);
                        acc[t] = a;
                    }
#pragma unroll
                    for (int t = 0; t < 4; ++t) {
                        acc[t] = __builtin_amdgcn_mfma_f32_16x16x32_bf16(ag0, bf2[t][0], acc[t], 0, 0, 0);
                        acc[t] = __builtin_amdgcn_mfma_f32_16x16x32_bf16(ag1, bf2[t][1], acc[t], 0, 0, 0);
                    }
                }
                // sigmoid + aggregation, lane-parallel in D-layout
#pragma unroll
                for (int r = 0; r < 4; ++r) {
                    bool valid = (lg * 4 + r) < cnt;
                    size_t hvr = (size_t)sA[r] * HH + l15;
#pragma unroll
                    for (int t = 0; t < 4; ++t) {
                        float sg = valid ? 1.f / (1.f + __expf(-acc[t][r])) : 0.f;
                        nmT[t] = fmaf(sg, b2f(hV[hvr + t * 16]), nmT[t]);
                        dnT[t] += sg;
                    }
                }
            }
        } // batches

        // one cross-lane reduce per dst, then layout-convert via wave-private LDS
        float* fl = (float*)lds;
        if constexpr (LAYER == 0) {
#pragma unroll
            for (int m = 1; m < 16; m <<= 1)
#pragma unroll
                for (int j = 0; j < 16; ++j) {
                    nmA[j] += __shfl_xor(nmA[j], m);
                    dnA[j] += __shfl_xor(dnA[j], m);
                }
            if (l15 == 0) {
#pragma unroll
                for (int j = 0; j < 8; ++j) {
                    fl[kb + j]      = nmA[j];
                    fl[32 + kb + j] = nmA[8 + j];
                    fl[64 + kb + j] = dnA[j];
                    fl[96 + kb + j] = dnA[8 + j];
                }
            }
        } else {
#pragma unroll
            for (int m = 16; m < 64; m <<= 1)
#pragma unroll
                for (int t = 0; t < 4; ++t) {
                    nmT[t] += __shfl_xor(nmT[t], m);
                    dnT[t] += __shfl_xor(dnT[t], m);
                }
            if (lg == 0) {
#pragma unroll
                for (int t = 0; t < 4; ++t) {
                    fl[t * 16 + l15]      = nmT[t];
                    fl[64 + t * 16 + l15] = dnT[t];
                }
            }
        }
        asm volatile("s_waitcnt lgkmcnt(0)" ::: "memory");
        float nmv = fl[lane], dnv = fl[64 + lane];

        // fused: h[d] = relu(h[d]@U_l + num/(den+1e-6)), 4-way ILP chain
        float hd = h[drow + lane];
        float h0 = 0.f, h1 = 0.f, h2 = 0.f, h3 = 0.f;
#pragma unroll
        for (int k = 0; k < HH; k += 4) {
            h0 = fmaf(bcast(hd, k),     Ul[k * HH + lane],       h0);
            h1 = fmaf(bcast(hd, k + 1), Ul[(k + 1) * HH + lane], h1);
            h2 = fmaf(bcast(hd, k + 2), Ul[(k + 2) * HH + lane], h2);
            h3 = fmaf(bcast(hd, k + 3), Ul[(k + 3) * HH + lane], h3);
        }
        h[drow + lane] = fmaxf((h0 + h1) + (h2 + h3) + nmv / (dnv + 1e-6f), 0.f);
    } // dsts
}

// ---------------- scoring ----------------
__global__ void score_k(const float* __restrict__ h, const float* __restrict__ Wp,
                        const float* __restrict__ bp, const int* __restrict__ ss,
                        const int* __restrict__ ds, float* __restrict__ out) {
    int lane = threadIdx.x & 63;
    int wave = (blockIdx.x * blockDim.x + threadIdx.x) >> 6;
    if (wave >= NS) return;
    int s = ss[wave], d = ds[wave];
    float v = fmaf(h[(size_t)s * HH + lane], Wp[lane],
                   h[(size_t)d * HH + lane] * Wp[HH + lane]);
#pragma unroll
    for (int off = 32; off; off >>= 1) v += __shfl_xor(v, off);
    if (lane == 0) out[wave] = v + bp[0];
}

extern "C" void kernel_launch(void* const* d_in, const int* in_sizes, int n_in,
                              void* d_out, int out_size, void* d_ws, size_t ws_size,
                              hipStream_t stream) {
    const float* x  = (const float*)d_in[0];
    const float* e0 = (const float*)d_in[1];
    const float* Wn = (const float*)d_in[2];
    const float* bn = (const float*)d_in[3];
    const float* We = (const float*)d_in[4];
    const float* be = (const float*)d_in[5];
    const float* A  = (const float*)d_in[6];
    const float* B  = (const float*)d_in[7];
    const float* C  = (const float*)d_in[8];
    const float* cb = (const float*)d_in[9];
    const float* U  = (const float*)d_in[10];
    const float* V  = (const float*)d_in[11];
    const float* Wp = (const float*)d_in[12];
    const float* bp = (const float*)d_in[13];
    const int* src  = (const int*)d_in[14];
    const int* dst  = (const int*)d_in[15];
    const int* ss   = (const int*)d_in[16];
    const int* ds   = (const int*)d_in[17];

    char* ws = (char*)d_ws;
    size_t nb = (size_t)NN * HH;
    float* h      = (float*)ws;                    // 25.6 MB
    bf16*  tabs   = (bf16*)(ws + nb * 4);          // 6 x 12.8 MB
    bf16*  hV     = tabs + 6 * nb;                 // 12.8 MB
    int*   perm   = (int*)(hV + nb);               // 6.4 MB
    int*   cnt    = perm + NE;
    int*   rowptr = cnt + NN;
    int*   cursor = rowptr + (NN + 1);
    int*   bsum   = cursor + NN;
    int*   bofs   = bsum + SCAN_G;
    float* We0    = (float*)(bofs + SCAN_G);
    float* bb0    = We0 + 2 * HH;

    encode_nodes_k<<<(NN * HH + 255) / 256, 256, 0, stream>>>(x, Wn, bn, h);
    prep_k<<<1, 64, 0, stream>>>(We, be, C, cb, We0, bb0);

    zero_int_k<<<(NN + 255) / 256, 256, 0, stream>>>(cnt, NN);
    hist_k<<<(NE + 255) / 256, 256, 0, stream>>>(dst, cnt);
    scan1_k<<<SCAN_G, SCAN_B, 0, stream>>>(cnt, rowptr, bsum);
    scan2_k<<<1, 64, 0, stream>>>(bsum, bofs);
    scan3_k<<<SCAN_G, SCAN_B, 0, stream>>>(rowptr, cursor, bofs);
    scatter_k<<<(NE + 255) / 256, 256, 0, stream>>>(dst, cursor, perm);

    int agrid = (NN + 4 * DPW - 1) / (4 * DPW);   // 6250
    for (int l = 0; l < 3; ++l) {
        node_transform_k<<<dim3(512, 3), 256, 0, stream>>>(
            h, A + (size_t)l * HH * HH, B + (size_t)l * HH * HH, V + (size_t)l * HH * HH,
            tabs + 2 * (size_t)l * nb, tabs + (2 * (size_t)l + 1) * nb, hV);
        const float* Ul = U + (size_t)l * HH * HH;
        if (l == 0)
            agg_k<0><<<agrid, 256, 0, stream>>>(h, tabs, hV, We0, bb0, cb, C, Ul,
                                                rowptr, perm, src, (const float2*)e0);
        else if (l == 1)
            agg_k<1><<<agrid, 256, 0, stream>>>(h, tabs, hV, We0, bb0, cb, C, Ul,
                                                rowptr, perm, src, (const float2*)e0);
        else
            agg_k<2><<<agrid, 256, 0, stream>>>(h, tabs, hV, We0, bb0, cb, C, Ul,
                                                rowptr, perm, src, (const float2*)e0);
    }

    score_k<<<(int)(((size_t)NS * HH + 255) / 256), 256, 0, stream>>>(
        h, Wp, bp, ss, ds, (float*)d_out);
}

// Round 8
// 1594.666 us; speedup vs baseline: 2.5533x; 1.6560x over previous
//
#include <hip/hip_runtime.h>
#include <hip/hip_bf16.h>

using bf16 = __hip_bfloat16;
typedef __attribute__((ext_vector_type(8))) short short8;  // 8 bf16 (4 VGPRs)
typedef __attribute__((ext_vector_type(4))) float f32x4;   // MFMA C/D
typedef __attribute__((ext_vector_type(4))) int   iv4;     // 16B of packed bf16

static constexpr int NN = 100000;   // nodes
static constexpr int NE = 1600000;  // message edges
static constexpr int NS = 500000;   // scored edges
static constexpr int HH = 64;       // hidden
static constexpr int SCAN_B = 1024;
static constexpr int SCAN_G = (NN + SCAN_B - 1) / SCAN_B;   // 98
static constexpr int DPW = 8;       // dsts per wave

__device__ __forceinline__ float b2f(bf16 v) { return __bfloat162float(v); }
__device__ __forceinline__ bf16  f2b(float v) { return __float2bfloat16(v); }
__device__ __forceinline__ float bflo(int u)  { return __uint_as_float(((unsigned)u) << 16); }
__device__ __forceinline__ float bfhi(int u)  { return __uint_as_float(((unsigned)u) & 0xffff0000u); }
__device__ __forceinline__ int pk2(float a, float b) {
    unsigned lo = __bfloat16_as_ushort(__float2bfloat16(a));
    unsigned hi = __bfloat16_as_ushort(__float2bfloat16(b));
    return (int)(lo | (hi << 16));
}
__device__ __forceinline__ float bcast(float v, int k) {
    return __uint_as_float(__builtin_amdgcn_readlane(__float_as_uint(v), k));
}
__device__ __forceinline__ int bcasti(int v, int k) {
    return __builtin_amdgcn_readlane(v, k);
}

// ---------------- encode + weight prep ----------------

__global__ void encode_nodes_k(const float* __restrict__ x, const float* __restrict__ Wn,
                               const float* __restrict__ bn, float* __restrict__ h) {
    int tid = blockIdx.x * blockDim.x + threadIdx.x;
    if (tid >= NN * HH) return;
    int r = tid >> 6, j = tid & 63;
    h[tid] = fmaf(x[2 * r], Wn[j], fmaf(x[2 * r + 1], Wn[HH + j], bn[j]));
}

// Fold edge encoder into layer-0 C: We0 = We@C0 (2x64), bb0 = be@C0 + cb0
__global__ void prep_k(const float* __restrict__ We, const float* __restrict__ be,
                       const float* __restrict__ C0, const float* __restrict__ cb0,
                       float* __restrict__ We0, float* __restrict__ bb0) {
    int j = threadIdx.x;
    if (j >= HH) return;
    float s0 = 0.f, s1 = 0.f, sb = 0.f;
    for (int k = 0; k < HH; ++k) {
        float c = C0[k * HH + j];
        s0 = fmaf(We[k], c, s0);
        s1 = fmaf(We[HH + k], c, s1);
        sb = fmaf(be[k], c, sb);
    }
    We0[j] = s0; We0[HH + j] = s1; bb0[j] = sb + cb0[j];
}

// ---------------- CSR build (counting sort by dst) ----------------

__global__ void zero_int_k(int* __restrict__ p, int n) {
    int i = blockIdx.x * blockDim.x + threadIdx.x;
    if (i < n) p[i] = 0;
}

__global__ void hist_k(const int* __restrict__ dst, int* __restrict__ cnt) {
    int i = blockIdx.x * blockDim.x + threadIdx.x;
    if (i < NE) atomicAdd(&cnt[dst[i]], 1);
}

__global__ void scan1_k(const int* __restrict__ cnt, int* __restrict__ rowptr,
                        int* __restrict__ bsum) {
    __shared__ int sm[SCAN_B];
    int t = threadIdx.x, idx = blockIdx.x * SCAN_B + t;
    int v = (idx < NN) ? cnt[idx] : 0;
    sm[t] = v;
    __syncthreads();
    for (int off = 1; off < SCAN_B; off <<= 1) {
        int add = (t >= off) ? sm[t - off] : 0;
        __syncthreads();
        sm[t] += add;
        __syncthreads();
    }
    if (idx < NN) rowptr[idx] = sm[t] - v;
    if (t == SCAN_B - 1) bsum[blockIdx.x] = sm[t];
}

__global__ void scan2_k(const int* __restrict__ bsum, int* __restrict__ bofs) {
    if (threadIdx.x == 0) {
        int acc = 0;
        for (int b = 0; b < SCAN_G; ++b) { bofs[b] = acc; acc += bsum[b]; }
    }
}

__global__ void scan3_k(int* __restrict__ rowptr, int* __restrict__ cursor,
                        const int* __restrict__ bofs) {
    int idx = blockIdx.x * SCAN_B + threadIdx.x;
    if (idx < NN) {
        int r = rowptr[idx] + bofs[blockIdx.x];
        rowptr[idx] = r;
        cursor[idx] = r;
    }
    if (idx == 0) rowptr[NN] = NE;
}

// builds 16-B records {src, e0.x, e0.y, 0} in dst-CSR order
__global__ void scatter_k(const int* __restrict__ dst, const int* __restrict__ src,
                          const float2* __restrict__ e0, int* __restrict__ cursor,
                          int4* __restrict__ sedge) {
    int i = blockIdx.x * blockDim.x + threadIdx.x;
    if (i < NE) {
        int p = atomicAdd(&cursor[dst[i]], 1);
        float2 ev = e0[i];
        sedge[p] = make_int4(src[i], __float_as_int(ev.x), __float_as_int(ev.y), 0);
    }
}

// ---------------- per-layer node transforms (A,B,V,U) ----------------
__global__ __launch_bounds__(256, 2)
void node_transform_k(const float* __restrict__ h, const float* __restrict__ A,
                      const float* __restrict__ B, const float* __restrict__ V,
                      const float* __restrict__ Ut,
                      bf16* __restrict__ oA, bf16* __restrict__ oB,
                      bf16* __restrict__ oV, bf16* __restrict__ oU) {
    int lane = threadIdx.x & 63;
    const float* W; bf16* out;
    if (blockIdx.y == 0)      { W = A;  out = oA; }
    else if (blockIdx.y == 1) { W = B;  out = oB; }
    else if (blockIdx.y == 2) { W = V;  out = oV; }
    else                      { W = Ut; out = oU; }
    float col[HH];
#pragma unroll
    for (int k = 0; k < HH; ++k) col[k] = W[k * HH + lane];
    int wave = blockIdx.x * (blockDim.x >> 6) + (threadIdx.x >> 6);
    int nw = gridDim.x * (blockDim.x >> 6);
    for (int r = wave; r < NN; r += nw) {
        const float* hr = h + (size_t)r * HH;
        float a0 = 0.f, a1 = 0.f, a2 = 0.f, a3 = 0.f;
#pragma unroll
        for (int k = 0; k < HH; k += 4) {
            a0 = fmaf(hr[k],     col[k],     a0);
            a1 = fmaf(hr[k + 1], col[k + 1], a1);
            a2 = fmaf(hr[k + 2], col[k + 2], a2);
            a3 = fmaf(hr[k + 3], col[k + 3], a3);
        }
        out[(size_t)r * HH + lane] = f2b((a0 + a1) + (a2 + a3));
    }
}

// ---------------- fused aggregate + node update ----------------
// tabs: [A0,B0,A1,B1,A2,B2,hV,hU] each [NN*64] bf16.
// A-frag: lane l -> edge=l&15, k=(l>>4)*8+j (+32)
// D:      lane l -> col=t*16+(l&15), row(edge)=(l>>4)*4+r
template <int LAYER>
__global__ __launch_bounds__(256, 2)
void agg_k(float* __restrict__ h, const bf16* __restrict__ tabs,
           const float* __restrict__ We0, const float* __restrict__ bb0,
           const float* __restrict__ cb, const float* __restrict__ C,
           const int* __restrict__ rowptr, const int4* __restrict__ sedge) {
    __shared__ __align__(16) char lds_all[4 * 8192];
    char* lds = lds_all + (threadIdx.x >> 6) * 8192;
    char* Lb1 = lds;            // hA1 rows, [16 edge][64 feat] bf16, xor-swizzled
    char* Lb2 = lds + 2048;     // hA2 rows (layer 2)
    char* Lhv = lds + 4096;     // hV rows
    char* Le1 = lds + 6144;     // e1 transpose (layer 2) + final f32 exchange
    const int lane = threadIdx.x & 63;
    const int l15 = lane & 15, lg = lane >> 4, kb = lg * 8;
    const size_t nb = (size_t)NN * HH;

    float w0a[8], w0b[8], w1a[8], w1b[8], bba[8], bbb[8];
#pragma unroll
    for (int j = 0; j < 8; ++j) {
        w0a[j] = We0[kb + j];        w0b[j] = We0[32 + kb + j];
        w1a[j] = We0[HH + kb + j];   w1b[j] = We0[HH + 32 + kb + j];
        bba[j] = bb0[kb + j];        bbb[j] = bb0[32 + kb + j];
    }
    short8 bf1[4][2], bf2[4][2];
    float cb1t[4], cb2t[4];
    if constexpr (LAYER >= 1) {
        const float* C1 = C + 1 * HH * HH;
#pragma unroll
        for (int t = 0; t < 4; ++t) {
            cb1t[t] = cb[HH + t * 16 + l15];
#pragma unroll
            for (int f = 0; f < 2; ++f) {
                iv4 q;
#pragma unroll
                for (int j = 0; j < 4; ++j)
                    q[j] = pk2(C1[(f * 32 + kb + 2 * j) * HH + t * 16 + l15],
                               C1[(f * 32 + kb + 2 * j + 1) * HH + t * 16 + l15]);
                __builtin_memcpy(&bf1[t][f], &q, 16);
            }
        }
    }
    if constexpr (LAYER >= 2) {
        const float* C2 = C + 2 * HH * HH;
#pragma unroll
        for (int t = 0; t < 4; ++t) {
            cb2t[t] = cb[2 * HH + t * 16 + l15];
#pragma unroll
            for (int f = 0; f < 2; ++f) {
                iv4 q;
#pragma unroll
                for (int j = 0; j < 4; ++j)
                    q[j] = pk2(C2[(f * 32 + kb + 2 * j) * HH + t * 16 + l15],
                               C2[(f * 32 + kb + 2 * j + 1) * HH + t * 16 + l15]);
                __builtin_memcpy(&bf2[t][f], &q, 16);
            }
        }
    }

    int w = blockIdx.x * 4 + (threadIdx.x >> 6);
    int dA = w * DPW;
    if (dA >= NN) return;
    int ndst = min(DPW, NN - dA);
    // preloaded rowptr window: lane j holds rowptr[dA+j] for j<=ndst
    int rpv = rowptr[dA + min(lane, ndst)];
    // prefetch first dst's first batch
    int4 cur;
    {
        int b0 = bcasti(rpv, 0), e0i = bcasti(rpv, 1);
        int idx = b0 + min(l15, max(e0i - b0 - 1, 0));
        cur = sedge[min(idx, NE - 1)];
    }
    const int wlo = (l15 * 128 + lg * 16) ^ ((l15 & 7) << 4);
    const int whi = (l15 * 128 + 64 + lg * 16) ^ ((l15 & 7) << 4);

    for (int i = 0; i < ndst; ++i) {
        int d = dA + i;
        int beg = bcasti(rpv, i), end = bcasti(rpv, i + 1);
        // prefetch next dst's first batch
        int4 nxt = cur;
        if (i + 1 < ndst) {
            int nb2 = bcasti(rpv, i + 1), ne2 = bcasti(rpv, i + 2);
            int idx = nb2 + min(l15, max(ne2 - nb2 - 1, 0));
            nxt = sedge[min(idx, NE - 1)];
        }
        size_t drow = (size_t)d * HH;
        float hu = b2f(tabs[7 * nb + drow + lane]);      // h@U row (precomputed)
        // per-dst biases
        float zba[8], zbb[8];
        {
            iv4 ra = *(const iv4*)(tabs + nb + drow + kb);
            iv4 rb = *(const iv4*)(tabs + nb + drow + 32 + kb);
#pragma unroll
            for (int q = 0; q < 4; ++q) {
                zba[2 * q]     = bba[2 * q]     + bflo(ra[q]);
                zba[2 * q + 1] = bba[2 * q + 1] + bfhi(ra[q]);
                zbb[2 * q]     = bbb[2 * q]     + bflo(rb[q]);
                zbb[2 * q + 1] = bbb[2 * q + 1] + bfhi(rb[q]);
            }
        }
        float c1d[4], c2d[4];
        if constexpr (LAYER >= 1) {
#pragma unroll
            for (int t = 0; t < 4; ++t)
                c1d[t] = cb1t[t] + b2f(tabs[3 * nb + drow + t * 16 + l15]);
        }
        if constexpr (LAYER >= 2) {
#pragma unroll
            for (int t = 0; t < 4; ++t)
                c2d[t] = cb2t[t] + b2f(tabs[5 * nb + drow + t * 16 + l15]);
        }

        float nmA[16], dnA[16], nmT[4], dnT[4];
        if constexpr (LAYER == 0) {
#pragma unroll
            for (int j = 0; j < 16; ++j) { nmA[j] = 0.f; dnA[j] = 0.f; }
        } else {
#pragma unroll
            for (int t = 0; t < 4; ++t) { nmT[t] = 0.f; dnT[t] = 0.f; }
        }

        for (int b = beg; b < end; b += 16) {
            int cnt = min(end - b, 16);
            int4 mine = cur;
            // prefetch next batch of this dst
            if (b + 16 < end) {
                int idx = b + 16 + min(l15, end - (b + 16) - 1);
                cur = sedge[idx];
            }
            int s = mine.x;
            float ex = __int_as_float(mine.y), ey = __int_as_float(mine.z);
            size_t srow = (size_t)s * HH;
            // row gathers (all independent, issued together)
            iv4 ra = *(const iv4*)(tabs + srow + kb);
            iv4 rb = *(const iv4*)(tabs + srow + 32 + kb);
            iv4 hva = *(const iv4*)(tabs + 6 * nb + srow + kb);
            iv4 hvb = *(const iv4*)(tabs + 6 * nb + srow + 32 + kb);
            iv4 b1a, b1b, b2a, b2b;
            if constexpr (LAYER >= 1) {
                b1a = *(const iv4*)(tabs + 2 * nb + srow + kb);
                b1b = *(const iv4*)(tabs + 2 * nb + srow + 32 + kb);
            }
            if constexpr (LAYER >= 2) {
                b2a = *(const iv4*)(tabs + 4 * nb + srow + kb);
                b2b = *(const iv4*)(tabs + 4 * nb + srow + 32 + kb);
            }
            // z0 in A-layout
            float za[8], zc[8];
#pragma unroll
            for (int q = 0; q < 4; ++q) {
                za[2*q]   = fmaf(ex, w0a[2*q],   fmaf(ey, w1a[2*q],   zba[2*q]))   + bflo(ra[q]);
                za[2*q+1] = fmaf(ex, w0a[2*q+1], fmaf(ey, w1a[2*q+1], zba[2*q+1])) + bfhi(ra[q]);
                zc[2*q]   = fmaf(ex, w0b[2*q],   fmaf(ey, w1b[2*q],   zbb[2*q]))   + bflo(rb[q]);
                zc[2*q+1] = fmaf(ex, w0b[2*q+1], fmaf(ey, w1b[2*q+1], zbb[2*q+1])) + bfhi(rb[q]);
            }
            if constexpr (LAYER == 0) {
                bool valid = (l15 < cnt);
#pragma unroll
                for (int q = 0; q < 4; ++q) {
                    float s00 = valid ? 1.f / (1.f + __expf(-za[2*q]))   : 0.f;
                    float s01 = valid ? 1.f / (1.f + __expf(-za[2*q+1])) : 0.f;
                    float s10 = valid ? 1.f / (1.f + __expf(-zc[2*q]))   : 0.f;
                    float s11 = valid ? 1.f / (1.f + __expf(-zc[2*q+1])) : 0.f;
                    nmA[2*q]     = fmaf(s00, bflo(hva[q]), nmA[2*q]);     dnA[2*q]     += s00;
                    nmA[2*q+1]   = fmaf(s01, bfhi(hva[q]), nmA[2*q+1]);   dnA[2*q+1]   += s01;
                    nmA[8+2*q]   = fmaf(s10, bflo(hvb[q]), nmA[8+2*q]);   dnA[8+2*q]   += s10;
                    nmA[8+2*q+1] = fmaf(s11, bfhi(hvb[q]), nmA[8+2*q+1]); dnA[8+2*q+1] += s11;
                }
            } else {
                // stage gathered rows into wave-private LDS (edge-major, swizzled)
                *(iv4*)(Lhv + wlo) = hva;  *(iv4*)(Lhv + whi) = hvb;
                *(iv4*)(Lb1 + wlo) = b1a;  *(iv4*)(Lb1 + whi) = b1b;
                if constexpr (LAYER >= 2) { *(iv4*)(Lb2 + wlo) = b2a; *(iv4*)(Lb2 + whi) = b2b; }
                // relu(z0) -> A-frags
                iv4 pa, pb;
#pragma unroll
                for (int q = 0; q < 4; ++q) {
                    pa[q] = pk2(fmaxf(za[2*q], 0.f), fmaxf(za[2*q+1], 0.f));
                    pb[q] = pk2(fmaxf(zc[2*q], 0.f), fmaxf(zc[2*q+1], 0.f));
                }
                short8 af0, af1;
                __builtin_memcpy(&af0, &pa, 16);
                __builtin_memcpy(&af1, &pb, 16);
                asm volatile("s_waitcnt lgkmcnt(0)" ::: "memory");
                // acc = cb1 + B1[d] + A1[src]  (D-layout), then e1 = A-frag @ C1
                f32x4 acc[4];
#pragma unroll
                for (int t = 0; t < 4; ++t) {
                    f32x4 a;
#pragma unroll
                    for (int r = 0; r < 4; ++r) {
                        int row = lg * 4 + r;
                        int ad = (row * 128 + (t * 16 + l15) * 2) ^ ((row & 7) << 4);
                        a[r] = c1d[t] + b2f(*(const bf16*)(Lb1 + ad));
                    }
                    acc[t] = a;
                }
#pragma unroll
                for (int t = 0; t < 4; ++t) {
                    acc[t] = __builtin_amdgcn_mfma_f32_16x16x32_bf16(af0, bf1[t][0], acc[t], 0, 0, 0);
                    acc[t] = __builtin_amdgcn_mfma_f32_16x16x32_bf16(af1, bf1[t][1], acc[t], 0, 0, 0);
                }
                if constexpr (LAYER >= 2) {
                    // relu(e_hat1): D-layout -> LDS -> A-frags
#pragma unroll
                    for (int t = 0; t < 4; ++t)
#pragma unroll
                        for (int r = 0; r < 4; ++r) {
                            int row = lg * 4 + r;
                            int ad = (row * 128 + (t * 16 + l15) * 2) ^ ((row & 7) << 4);
                            *(unsigned short*)(Le1 + ad) =
                                __bfloat16_as_ushort(__float2bfloat16(fmaxf(acc[t][r], 0.f)));
                        }
                    asm volatile("s_waitcnt lgkmcnt(0)" ::: "memory");
                    short8 ag0, ag1;
                    __builtin_memcpy(&ag0, Le1 + ((l15 * 128 + kb * 2) ^ ((l15 & 7) << 4)), 16);
                    __builtin_memcpy(&ag1, Le1 + ((l15 * 128 + 64 + kb * 2) ^ ((l15 & 7) << 4)), 16);
#pragma unroll
                    for (int t = 0; t < 4; ++t) {
                        f32x4 a;
#pragma unroll
                        for (int r = 0; r < 4; ++r) {
                            int row = lg * 4 + r;
                            int ad = (row * 128 + (t * 16 + l15) * 2) ^ ((row & 7) << 4);
                            a[r] = c2d[t] + b2f(*(const bf16*)(Lb2 + ad));
                        }
                        acc[t] = a;
                    }
#pragma unroll
                    for (int t = 0; t < 4; ++t) {
                        acc[t] = __builtin_amdgcn_mfma_f32_16x16x32_bf16(ag0, bf2[t][0], acc[t], 0, 0, 0);
                        acc[t] = __builtin_amdgcn_mfma_f32_16x16x32_bf16(ag1, bf2[t][1], acc[t], 0, 0, 0);
                    }
                }
                // sigmoid + aggregate (D-layout, hV from LDS)
#pragma unroll
                for (int r = 0; r < 4; ++r) {
                    int row = lg * 4 + r;
                    bool valid = row < cnt;
#pragma unroll
                    for (int t = 0; t < 4; ++t) {
                        float sg = valid ? 1.f / (1.f + __expf(-acc[t][r])) : 0.f;
                        int ad = (row * 128 + (t * 16 + l15) * 2) ^ ((row & 7) << 4);
                        nmT[t] = fmaf(sg, b2f(*(const bf16*)(Lhv + ad)), nmT[t]);
                        dnT[t] += sg;
                    }
                }
            }
        } // batches

        // cross-lane reduce + exchange, then h update with precomputed hU
        float* fl = (float*)Le1;
        if constexpr (LAYER == 0) {
#pragma unroll
            for (int m = 1; m < 16; m <<= 1)
#pragma unroll
                for (int j = 0; j < 16; ++j) {
                    nmA[j] += __shfl_xor(nmA[j], m);
                    dnA[j] += __shfl_xor(dnA[j], m);
                }
            if (l15 == 0) {
#pragma unroll
                for (int j = 0; j < 8; ++j) {
                    fl[kb + j]      = nmA[j];
                    fl[32 + kb + j] = nmA[8 + j];
                    fl[64 + kb + j] = dnA[j];
                    fl[96 + kb + j] = dnA[8 + j];
                }
            }
        } else {
#pragma unroll
            for (int m = 16; m < 64; m <<= 1)
#pragma unroll
                for (int t = 0; t < 4; ++t) {
                    nmT[t] += __shfl_xor(nmT[t], m);
                    dnT[t] += __shfl_xor(dnT[t], m);
                }
            if (lg == 0) {
#pragma unroll
                for (int t = 0; t < 4; ++t) {
                    fl[t * 16 + l15]      = nmT[t];
                    fl[64 + t * 16 + l15] = dnT[t];
                }
            }
        }
        asm volatile("s_waitcnt lgkmcnt(0)" ::: "memory");
        float nmv = fl[lane], dnv = fl[64 + lane];
        h[drow + lane] = fmaxf(hu + nmv / (dnv + 1e-6f), 0.f);
        cur = nxt;
    } // dsts
}

// ---------------- scoring ----------------
__global__ void score_k(const float* __restrict__ h, const float* __restrict__ Wp,
                        const float* __restrict__ bp, const int* __restrict__ ss,
                        const int* __restrict__ ds, float* __restrict__ out) {
    int lane = threadIdx.x & 63;
    int wave = (blockIdx.x * blockDim.x + threadIdx.x) >> 6;
    if (wave >= NS) return;
    int s = ss[wave], d = ds[wave];
    float v = fmaf(h[(size_t)s * HH + lane], Wp[lane],
                   h[(size_t)d * HH + lane] * Wp[HH + lane]);
#pragma unroll
    for (int off = 32; off; off >>= 1) v += __shfl_xor(v, off);
    if (lane == 0) out[wave] = v + bp[0];
}

extern "C" void kernel_launch(void* const* d_in, const int* in_sizes, int n_in,
                              void* d_out, int out_size, void* d_ws, size_t ws_size,
                              hipStream_t stream) {
    const float* x  = (const float*)d_in[0];
    const float* e0 = (const float*)d_in[1];
    const float* Wn = (const float*)d_in[2];
    const float* bn = (const float*)d_in[3];
    const float* We = (const float*)d_in[4];
    const float* be = (const float*)d_in[5];
    const float* A  = (const float*)d_in[6];
    const float* B  = (const float*)d_in[7];
    const float* C  = (const float*)d_in[8];
    const float* cb = (const float*)d_in[9];
    const float* U  = (const float*)d_in[10];
    const float* V  = (const float*)d_in[11];
    const float* Wp = (const float*)d_in[12];
    const float* bp = (const float*)d_in[13];
    const int* src  = (const int*)d_in[14];
    const int* dst  = (const int*)d_in[15];
    const int* ss   = (const int*)d_in[16];
    const int* ds   = (const int*)d_in[17];

    char* ws = (char*)d_ws;
    size_t nb = (size_t)NN * HH;
    float* h      = (float*)ws;                    // 25.6 MB
    bf16*  tabs   = (bf16*)(ws + nb * 4);          // 8 x 12.8 MB  [A0,B0,A1,B1,A2,B2,hV,hU]
    int4*  sedge  = (int4*)(tabs + 8 * nb);        // 25.6 MB
    int*   cnt    = (int*)(sedge + NE);
    int*   rowptr = cnt + NN;
    int*   cursor = rowptr + (NN + 1);
    int*   bsum   = cursor + NN;
    int*   bofs   = bsum + SCAN_G;
    float* We0    = (float*)(bofs + SCAN_G);
    float* bb0    = We0 + 2 * HH;

    encode_nodes_k<<<(NN * HH + 255) / 256, 256, 0, stream>>>(x, Wn, bn, h);
    prep_k<<<1, 64, 0, stream>>>(We, be, C, cb, We0, bb0);

    zero_int_k<<<(NN + 255) / 256, 256, 0, stream>>>(cnt, NN);
    hist_k<<<(NE + 255) / 256, 256, 0, stream>>>(dst, cnt);
    scan1_k<<<SCAN_G, SCAN_B, 0, stream>>>(cnt, rowptr, bsum);
    scan2_k<<<1, 64, 0, stream>>>(bsum, bofs);
    scan3_k<<<SCAN_G, SCAN_B, 0, stream>>>(rowptr, cursor, bofs);
    scatter_k<<<(NE + 255) / 256, 256, 0, stream>>>(dst, src, (const float2*)e0,
                                                    cursor, sedge);

    int agrid = (NN + 4 * DPW - 1) / (4 * DPW);   // 3125
    for (int l = 0; l < 3; ++l) {
        node_transform_k<<<dim3(512, 4), 256, 0, stream>>>(
            h, A + (size_t)l * HH * HH, B + (size_t)l * HH * HH,
            V + (size_t)l * HH * HH, U + (size_t)l * HH * HH,
            tabs + 2 * (size_t)l * nb, tabs + (2 * (size_t)l + 1) * nb,
            tabs + 6 * nb, tabs + 7 * nb);
        if (l == 0)
            agg_k<0><<<agrid, 256, 0, stream>>>(h, tabs, We0, bb0, cb, C, rowptr, sedge);
        else if (l == 1)
            agg_k<1><<<agrid, 256, 0, stream>>>(h, tabs, We0, bb0, cb, C, rowptr, sedge);
        else
            agg_k<2><<<agrid, 256, 0, stream>>>(h, tabs, We0, bb0, cb, C, rowptr, sedge);
    }

    score_k<<<(int)(((size_t)NS * HH + 255) / 256), 256, 0, stream>>>(
        h, Wp, bp, ss, ds, (float*)d_out);
}